// Round 2
// baseline (618.478 us; speedup 1.0000x reference)
//
#include <hip/hip_runtime.h>

#define NN 8192
#define FIN 256
#define FO 64
#define MAXNBR 1024

typedef unsigned short u16;
typedef unsigned int u32;

__device__ __forceinline__ float b2f(u16 u){
    return __uint_as_float(((u32)u) << 16);
}
__device__ __forceinline__ u16 f2b(float f){
    u32 u = __float_as_uint(f);
    u32 r = u + 0x7FFFu + ((u >> 16) & 1u);   // round-to-nearest-even
    return (u16)(r >> 16);
}

// dtype probe: A[0][0] == 1.0 guaranteed (self-loop diagonal).
// f32 -> first u32 = 0x3F800000 (low16 == 0). bf16 -> low16 = 0x3F80 != 0.
__device__ __forceinline__ bool probe_is_bf16(const void* A){
    u32 v = *(const u32*)A;
    return (v & 0xFFFFu) != 0u;
}

// ---------------- Kernel 1: feats[h][n][o] = sum_f X[n][f] * W[h][f][o] ----------------
// grid (NN/32, 2), block 256. Two k-phases of 128; f32 LDS tiles (Ws 32KB + Xs 16.5KB).
template<bool BF16>
__global__ __launch_bounds__(256) void feats_kernel(
    const void* __restrict__ Xv,    // [8192][256]
    const void* __restrict__ Wv,    // [2][256][64]
    const void* __restrict__ Av,    // probe only
    float* __restrict__ feats)      // [2][8192][64] fp32
{
    if (probe_is_bf16(Av) != BF16) return;

    __shared__ float Ws[128*FO];    // [k][o], 32KB
    __shared__ float Xs[32*132];    // [r][k], stride 132
    const int h = blockIdx.y;
    const int row0 = blockIdx.x * 32;
    const int t = threadIdx.x;

    const int rg = t >> 4;           // 0..15 -> rows rg*2, rg*2+1
    const int c0 = (t & 15) << 2;    // 0..60
    float acc0[4] = {0.f,0.f,0.f,0.f};
    float acc1[4] = {0.f,0.f,0.f,0.f};

    for (int kp = 0; kp < 2; ++kp){
        const int kb = kp * 128;
        // ---- stage W[h][kb:kb+128][:] -> Ws (8192 floats) ----
        if (BF16){
            const u16* Wh = (const u16*)Wv + h*FIN*FO + kb*FO;
            #pragma unroll
            for (int it=0; it<8; ++it){
                int flat = (it*256 + t)*4;
                ushort4 w4 = *(const ushort4*)&Wh[flat];
                Ws[flat+0]=b2f(w4.x); Ws[flat+1]=b2f(w4.y);
                Ws[flat+2]=b2f(w4.z); Ws[flat+3]=b2f(w4.w);
            }
        } else {
            const float* Wh = (const float*)Wv + h*FIN*FO + kb*FO;
            #pragma unroll
            for (int it=0; it<8; ++it){
                int flat = (it*256 + t)*4;
                *(float4*)&Ws[flat] = *(const float4*)&Wh[flat];
            }
        }
        // ---- stage X[row0:row0+32][kb:kb+128] -> Xs (4096 floats) ----
        if (BF16){
            const u16* Xp = (const u16*)Xv;
            #pragma unroll
            for (int it=0; it<4; ++it){
                int flat = (it*256 + t)*4;
                int r = flat >> 7, f0 = flat & 127;
                ushort4 x4 = *(const ushort4*)&Xp[(size_t)(row0+r)*FIN + kb + f0];
                float* dst = &Xs[r*132 + f0];
                dst[0]=b2f(x4.x); dst[1]=b2f(x4.y); dst[2]=b2f(x4.z); dst[3]=b2f(x4.w);
            }
        } else {
            const float* Xp = (const float*)Xv;
            #pragma unroll
            for (int it=0; it<4; ++it){
                int flat = (it*256 + t)*4;
                int r = flat >> 7, f0 = flat & 127;
                *(float4*)&Xs[r*132 + f0] = *(const float4*)&Xp[(size_t)(row0+r)*FIN + kb + f0];
            }
        }
        __syncthreads();

        const float* xp0 = &Xs[(rg*2+0)*132];
        const float* xp1 = &Xs[(rg*2+1)*132];
        #pragma unroll 4
        for (int k=0; k<128; ++k){
            float x0 = xp0[k];
            float x1 = xp1[k];
            float4 w4 = *(const float4*)&Ws[k*FO + c0];
            acc0[0]=fmaf(x0,w4.x,acc0[0]); acc0[1]=fmaf(x0,w4.y,acc0[1]);
            acc0[2]=fmaf(x0,w4.z,acc0[2]); acc0[3]=fmaf(x0,w4.w,acc0[3]);
            acc1[0]=fmaf(x1,w4.x,acc1[0]); acc1[1]=fmaf(x1,w4.y,acc1[1]);
            acc1[2]=fmaf(x1,w4.z,acc1[2]); acc1[3]=fmaf(x1,w4.w,acc1[3]);
        }
        __syncthreads();
    }

    float* o0 = feats + (size_t)h*NN*FO + (size_t)(row0 + rg*2 + 0)*FO + c0;
    float* o1 = feats + (size_t)h*NN*FO + (size_t)(row0 + rg*2 + 1)*FO + c0;
    *(float4*)o0 = make_float4(acc0[0],acc0[1],acc0[2],acc0[3]);
    *(float4*)o1 = make_float4(acc1[0],acc1[1],acc1[2],acc1[3]);
}

// ---------------- Kernel 2: sparse masked attention, one block (256 thr) per row i ----------------
template<bool BF16>
__global__ __launch_bounds__(256) void attn_kernel(
    const void* __restrict__ Av,    // [8192][8192], exact 0/1
    const void* __restrict__ av,    // [2][64]
    const void* __restrict__ bv,    // [2][64]
    const float* __restrict__ feats,// [2][8192][64] fp32
    void* __restrict__ outv)        // [8192][128]
{
    if (probe_is_bf16(Av) != BF16) return;

    __shared__ int   nbrs[MAXNBR];
    __shared__ float sc0[MAXNBR];
    __shared__ float sc1[MAXNBR];
    __shared__ float q[2*FO];
    __shared__ float part[128];
    __shared__ float redA[4], redB[4], redC[4], redD[4];
    __shared__ int cnt;

    const int i = blockIdx.x;
    const int t = threadIdx.x;
    if (t == 0) cnt = 0;
    if (t < 128){
        int h = t >> 6, o = t & 63;
        float a_ho = BF16 ? b2f(((const u16*)av)[t]) : ((const float*)av)[t];
        q[t] = feats[(size_t)h*NN*FO + (size_t)i*FO + o] * a_ho;
    }
    __syncthreads();

    // --- scan adjacency row (coalesced 16B/lane), build neighbor list ---
    if (BF16){
        const u16* Arow = (const u16*)Av + (size_t)i * NN;
        #pragma unroll
        for (int c2=0; c2<4; ++c2){
            int col0 = c2*2048 + t*8;
            uint4 v = *(const uint4*)&Arow[col0];
            const u16* pv = (const u16*)&v;
            #pragma unroll
            for (int e=0; e<8; ++e){
                if (pv[e] != 0){
                    int pos = atomicAdd(&cnt, 1);
                    if (pos < MAXNBR) nbrs[pos] = col0 + e;
                }
            }
        }
    } else {
        const float* Arow = (const float*)Av + (size_t)i * NN;
        #pragma unroll
        for (int c2=0; c2<8; ++c2){
            int col0 = c2*1024 + t*4;
            float4 v = *(const float4*)&Arow[col0];
            const float* pv = (const float*)&v;
            #pragma unroll
            for (int e=0; e<4; ++e){
                if (pv[e] != 0.0f){
                    int pos = atomicAdd(&cnt, 1);
                    if (pos < MAXNBR) nbrs[pos] = col0 + e;
                }
            }
        }
    }
    __syncthreads();
    const int n = min(cnt, MAXNBR);

    // --- scores: s[h] = dot64(q[h], feats[h][j]) , leaky relu ---
    float vmax0 = -1e30f, vmax1 = -1e30f;
    for (int k=t; k<n; k+=256){
        int j = nbrs[k];
        const float4* f0 = (const float4*)(feats + (size_t)j*FO);
        const float4* f1 = (const float4*)(feats + (size_t)NN*FO + (size_t)j*FO);
        const float4* q0 = (const float4*)q;
        const float4* q1 = (const float4*)(q + FO);
        float s0 = 0.f, s1 = 0.f;
        #pragma unroll
        for (int m=0; m<16; ++m){
            float4 a0=f0[m], b0=q0[m];
            float4 a1=f1[m], b1=q1[m];
            s0 += a0.x*b0.x + a0.y*b0.y + a0.z*b0.z + a0.w*b0.w;
            s1 += a1.x*b1.x + a1.y*b1.y + a1.z*b1.z + a1.w*b1.w;
        }
        s0 = (s0 >= 0.f) ? s0 : 0.2f*s0;
        s1 = (s1 >= 0.f) ? s1 : 0.2f*s1;
        sc0[k] = s0; sc1[k] = s1;
        vmax0 = fmaxf(vmax0, s0); vmax1 = fmaxf(vmax1, s1);
    }
    #pragma unroll
    for (int off=32; off; off>>=1){
        vmax0 = fmaxf(vmax0, __shfl_down(vmax0, off, 64));
        vmax1 = fmaxf(vmax1, __shfl_down(vmax1, off, 64));
    }
    if ((t & 63) == 0){ redA[t>>6] = vmax0; redB[t>>6] = vmax1; }
    __syncthreads();
    const float m0 = fmaxf(fmaxf(redA[0],redA[1]), fmaxf(redA[2],redA[3]));
    const float m1 = fmaxf(fmaxf(redB[0],redB[1]), fmaxf(redB[2],redB[3]));

    // --- exp + sum ---
    float sum0 = 0.f, sum1 = 0.f;
    for (int k=t; k<n; k+=256){
        float p0 = __expf(sc0[k] - m0); sc0[k] = p0; sum0 += p0;
        float p1 = __expf(sc1[k] - m1); sc1[k] = p1; sum1 += p1;
    }
    #pragma unroll
    for (int off=32; off; off>>=1){
        sum0 += __shfl_down(sum0, off, 64);
        sum1 += __shfl_down(sum1, off, 64);
    }
    if ((t & 63) == 0){ redC[t>>6] = sum0; redD[t>>6] = sum1; }
    __syncthreads();
    const float S0 = redC[0]+redC[1]+redC[2]+redC[3];
    const float S1 = redD[0]+redD[1]+redD[2]+redD[3];

    // --- aggregate: out[i][h*64+o] = relu((sum_k p_k * feats[h][j_k][o]) / S_h + b[h][o]) ---
    const int g  = t >> 7;          // 0/1 split over k
    const int t2 = t & 127;
    const int h  = t2 >> 6, o = t2 & 63;
    const float* Fh  = feats + (size_t)h*NN*FO;
    const float* scp = h ? sc1 : sc0;
    float acc = 0.f;
    for (int k=g; k<n; k+=2) acc = fmaf(scp[k], Fh[(size_t)nbrs[k]*FO + o], acc);
    if (g == 1) part[t2] = acc;
    __syncthreads();
    if (g == 0){
        acc += part[t2];
        float inv = 1.0f / (h ? S1 : S0);
        float b_ho = BF16 ? b2f(((const u16*)bv)[t2]) : ((const float*)bv)[t2];
        float val = acc * inv + b_ho;
        val = fmaxf(val, 0.f);
        if (BF16) ((u16*)outv)[(size_t)i*128 + t2] = f2b(val);
        else      ((float*)outv)[(size_t)i*128 + t2] = val;
    }
}

extern "C" void kernel_launch(void* const* d_in, const int* in_sizes, int n_in,
                              void* d_out, int out_size, void* d_ws, size_t ws_size,
                              hipStream_t stream) {
    const void* X = d_in[0];   // [8192,256]
    const void* A = d_in[1];   // [8192,8192]
    const void* W = d_in[2];   // [2,256,64]
    const void* b = d_in[3];   // [2,64]
    const void* a = d_in[4];   // [2,64]
    float* feats = (float*)d_ws;          // 4 MB fp32 scratch

    // dtype decided on-device by probing A[0][0]; mismatched template exits immediately.
    feats_kernel<false><<<dim3(NN/32, 2), 256, 0, stream>>>(X, W, A, feats);
    feats_kernel<true ><<<dim3(NN/32, 2), 256, 0, stream>>>(X, W, A, feats);
    attn_kernel<false><<<dim3(NN), 256, 0, stream>>>(A, a, b, feats, d_out);
    attn_kernel<true ><<<dim3(NN), 256, 0, stream>>>(A, a, b, feats, d_out);
}

// Round 3
// 486.820 us; speedup vs baseline: 1.2704x; 1.2704x over previous
//
#include <hip/hip_runtime.h>

#define NN 8192
#define FIN 256
#define FO 64
#define CAP 192   // max neighbors per row (mean ~82, ~11 sigma headroom)

// ---------------- Kernel 1: feats[n][h][o] = sum_f X[n][f] * W[h][f][o] ----------------
// grid (NN/32, 2), block 256. f32 LDS tiles, two k-phases of 128.
__global__ __launch_bounds__(256) void feats_kernel(
    const float* __restrict__ X,     // [8192][256]
    const float* __restrict__ W,     // [2][256][64]
    float* __restrict__ feats)       // [8192][2][64] fp32 (heads interleaved)
{
    __shared__ float Ws[128*FO];     // [k][o], 32KB
    __shared__ float Xs[32*132];     // [r][k], stride 132 (conflict-free)
    const int h = blockIdx.y;
    const int row0 = blockIdx.x * 32;
    const int t = threadIdx.x;
    const int rg = t >> 4;           // row pair 0..15
    const int c0 = (t & 15) << 2;    // col 0..60
    float acc0[4] = {0.f,0.f,0.f,0.f};
    float acc1[4] = {0.f,0.f,0.f,0.f};

    for (int kp = 0; kp < 2; ++kp){
        const int kb = kp * 128;
        const float* Wh = W + h*FIN*FO + kb*FO;
        #pragma unroll
        for (int it=0; it<8; ++it){
            int flat = (it*256 + t)*4;
            *(float4*)&Ws[flat] = *(const float4*)&Wh[flat];
        }
        #pragma unroll
        for (int it=0; it<4; ++it){
            int flat = (it*256 + t)*4;
            int r = flat >> 7, f0 = flat & 127;
            *(float4*)&Xs[r*132 + f0] = *(const float4*)&X[(size_t)(row0+r)*FIN + kb + f0];
        }
        __syncthreads();
        const float* xp0 = &Xs[(rg*2+0)*132];
        const float* xp1 = &Xs[(rg*2+1)*132];
        #pragma unroll 4
        for (int k=0; k<128; ++k){
            float x0 = xp0[k], x1 = xp1[k];
            float4 w4 = *(const float4*)&Ws[k*FO + c0];
            acc0[0]=fmaf(x0,w4.x,acc0[0]); acc0[1]=fmaf(x0,w4.y,acc0[1]);
            acc0[2]=fmaf(x0,w4.z,acc0[2]); acc0[3]=fmaf(x0,w4.w,acc0[3]);
            acc1[0]=fmaf(x1,w4.x,acc1[0]); acc1[1]=fmaf(x1,w4.y,acc1[1]);
            acc1[2]=fmaf(x1,w4.z,acc1[2]); acc1[3]=fmaf(x1,w4.w,acc1[3]);
        }
        __syncthreads();
    }
    float* o0 = feats + ((size_t)(row0 + rg*2 + 0)*2 + h)*FO + c0;
    float* o1 = feats + ((size_t)(row0 + rg*2 + 1)*2 + h)*FO + c0;
    *(float4*)o0 = make_float4(acc0[0],acc0[1],acc0[2],acc0[3]);
    *(float4*)o1 = make_float4(acc1[0],acc1[1],acc1[2],acc1[3]);
}

// ---------------- Kernel 2: CSR build — pure streaming scan of A ----------------
// one block (256 thr) per row; only job is reading A at full HBM BW.
__global__ __launch_bounds__(256) void csr_kernel(
    const float* __restrict__ A,     // [8192][8192] exact 0/1
    int* __restrict__ cnt,           // [8192]
    int* __restrict__ nbr)           // [8192][CAP]
{
    __shared__ int s_n[CAP];
    __shared__ int s_c;
    const int i = blockIdx.x, t = threadIdx.x;
    if (t == 0) s_c = 0;
    __syncthreads();
    const float* Arow = A + (size_t)i * NN;
    #pragma unroll
    for (int c=0; c<8; ++c){
        int col0 = c*1024 + t*4;
        float4 v = *(const float4*)&Arow[col0];
        if (v.x != 0.f){ int p = atomicAdd(&s_c,1); if (p < CAP) s_n[p] = col0;   }
        if (v.y != 0.f){ int p = atomicAdd(&s_c,1); if (p < CAP) s_n[p] = col0+1; }
        if (v.z != 0.f){ int p = atomicAdd(&s_c,1); if (p < CAP) s_n[p] = col0+2; }
        if (v.w != 0.f){ int p = atomicAdd(&s_c,1); if (p < CAP) s_n[p] = col0+3; }
    }
    __syncthreads();
    int n = min(s_c, CAP);
    if (t == 0) cnt[i] = n;
    for (int k=t; k<n; k+=256) nbr[(size_t)i*CAP + k] = s_n[k];
}

// ---------------- Kernel 3: wave-per-row sparse attention (no block barriers) ----------------
__global__ __launch_bounds__(256) void attn_kernel(
    const float* __restrict__ feats, // [8192][2][64]
    const float* __restrict__ av,    // [2][64]
    const float* __restrict__ bv,    // [2][64]
    const int* __restrict__ cnt,
    const int* __restrict__ nbr,
    float* __restrict__ out)         // [8192][128]
{
    __shared__ float qsh[4][128];       // per-wave q (both heads)
    __shared__ float psh[4][2][CAP];    // per-wave softmax numerators
    __shared__ int   nsh[4][CAP];       // per-wave neighbor ids
    const int t = threadIdx.x, w = t >> 6, lane = t & 63;
    const int i = blockIdx.x*4 + w;

    float q0 = feats[((size_t)i*2 + 0)*FO + lane] * av[lane];
    float q1 = feats[((size_t)i*2 + 1)*FO + lane] * av[64 + lane];
    qsh[w][lane] = q0; qsh[w][64 + lane] = q1;
    __threadfence_block();              // order LDS write -> cross-lane read (wave-local)

    const int n = cnt[i];
    const int* nb = nbr + (size_t)i*CAP;
    const int nch = (n + 63) >> 6;      // <= 3

    // --- scores, lane-per-neighbor; raw scores kept in registers per chunk ---
    float s0r[3], s1r[3];
    float m0 = -1e30f, m1 = -1e30f;
    for (int c=0; c<nch; ++c){
        int k = c*64 + lane;
        bool valid = k < n;
        int j = valid ? nb[k] : i;
        if (valid) nsh[w][k] = j;
        const float4* f  = (const float4*)(feats + (size_t)j*2*FO);
        const float4* qp = (const float4*)qsh[w];
        float s0 = 0.f, s1 = 0.f;
        #pragma unroll
        for (int m=0; m<16; ++m){
            float4 a0 = f[m],    b0 = qp[m];
            float4 a1 = f[16+m], b1 = qp[16+m];
            s0 += a0.x*b0.x + a0.y*b0.y + a0.z*b0.z + a0.w*b0.w;
            s1 += a1.x*b1.x + a1.y*b1.y + a1.z*b1.z + a1.w*b1.w;
        }
        s0 = (s0 >= 0.f) ? s0 : 0.2f*s0;
        s1 = (s1 >= 0.f) ? s1 : 0.2f*s1;
        if (!valid){ s0 = -1e30f; s1 = -1e30f; }
        s0r[c] = s0; s1r[c] = s1;
        m0 = fmaxf(m0, s0); m1 = fmaxf(m1, s1);
    }
    #pragma unroll
    for (int off=32; off; off>>=1){
        m0 = fmaxf(m0, __shfl_xor(m0, off, 64));
        m1 = fmaxf(m1, __shfl_xor(m1, off, 64));
    }

    // --- exp + sum (register chunks -> LDS numerators) ---
    float sum0 = 0.f, sum1 = 0.f;
    for (int c=0; c<nch; ++c){
        int k = c*64 + lane;
        bool valid = k < n;
        float p0 = valid ? __expf(s0r[c] - m0) : 0.f;
        float p1 = valid ? __expf(s1r[c] - m1) : 0.f;
        if (valid){ psh[w][0][k] = p0; psh[w][1][k] = p1; }
        sum0 += p0; sum1 += p1;
    }
    #pragma unroll
    for (int off=32; off; off>>=1){
        sum0 += __shfl_xor(sum0, off, 64);
        sum1 += __shfl_xor(sum1, off, 64);
    }
    __threadfence_block();

    // --- aggregate: lane = o; coalesced 512B/neighbor ---
    float acc0 = 0.f, acc1 = 0.f;
    for (int k=0; k<n; ++k){
        int j = nsh[w][k];
        float p0 = psh[w][0][k], p1 = psh[w][1][k];
        const float* fj = feats + (size_t)j*2*FO;
        acc0 = fmaf(p0, fj[lane],      acc0);
        acc1 = fmaf(p1, fj[64 + lane], acc1);
    }
    float v0 = fmaxf(acc0 / sum0 + bv[lane],      0.f);
    float v1 = fmaxf(acc1 / sum1 + bv[64 + lane], 0.f);
    out[(size_t)i*128 + lane]      = v0;
    out[(size_t)i*128 + 64 + lane] = v1;
}

extern "C" void kernel_launch(void* const* d_in, const int* in_sizes, int n_in,
                              void* d_out, int out_size, void* d_ws, size_t ws_size,
                              hipStream_t stream) {
    const float* X = (const float*)d_in[0];   // [8192,256]
    const float* A = (const float*)d_in[1];   // [8192,8192]
    const float* W = (const float*)d_in[2];   // [2,256,64]
    const float* b = (const float*)d_in[3];   // [2,64]
    const float* a = (const float*)d_in[4];   // [2,64]
    float* out = (float*)d_out;               // [8192,128]

    char* ws = (char*)d_ws;
    float* feats = (float*)ws;                          // 4 MB
    int*   cnt   = (int*)(ws + (size_t)NN*2*FO*4);      // 32 KB
    int*   nbrs  = (int*)(ws + (size_t)NN*2*FO*4 + NN*4); // 6 MB

    feats_kernel<<<dim3(NN/32, 2), 256, 0, stream>>>(X, W, feats);
    csr_kernel  <<<dim3(NN),       256, 0, stream>>>(A, cnt, nbrs);
    attn_kernel <<<dim3(NN/4),     256, 0, stream>>>(feats, a, b, cnt, nbrs, out);
}

// Round 4
// 469.753 us; speedup vs baseline: 1.3166x; 1.0363x over previous
//
#include <hip/hip_runtime.h>

#define NN 8192
#define FIN 256
#define FO 64
#define CAP 192   // max neighbors per row (mean ~82, >10 sigma headroom)

// ---------------- Kernel 1: feats[n][h][o] = sum_f X[n][f] * W[h][f][o] ----------------
__global__ __launch_bounds__(256) void feats_kernel(
    const float* __restrict__ X,     // [8192][256]
    const float* __restrict__ W,     // [2][256][64]
    float* __restrict__ feats)       // [8192][2][64] (heads interleaved per node)
{
    __shared__ float Ws[128*FO];     // [k][o], 32KB
    __shared__ float Xs[32*132];     // [r][k], stride 132
    const int h = blockIdx.y;
    const int row0 = blockIdx.x * 32;
    const int t = threadIdx.x;
    const int rg = t >> 4;
    const int c0 = (t & 15) << 2;
    float acc0[4] = {0.f,0.f,0.f,0.f};
    float acc1[4] = {0.f,0.f,0.f,0.f};

    for (int kp = 0; kp < 2; ++kp){
        const int kb = kp * 128;
        const float* Wh = W + h*FIN*FO + kb*FO;
        #pragma unroll
        for (int it=0; it<8; ++it){
            int flat = (it*256 + t)*4;
            *(float4*)&Ws[flat] = *(const float4*)&Wh[flat];
        }
        #pragma unroll
        for (int it=0; it<4; ++it){
            int flat = (it*256 + t)*4;
            int r = flat >> 7, f0 = flat & 127;
            *(float4*)&Xs[r*132 + f0] = *(const float4*)&X[(size_t)(row0+r)*FIN + kb + f0];
        }
        __syncthreads();
        const float* xp0 = &Xs[(rg*2+0)*132];
        const float* xp1 = &Xs[(rg*2+1)*132];
        #pragma unroll 4
        for (int k=0; k<128; ++k){
            float x0 = xp0[k], x1 = xp1[k];
            float4 w4 = *(const float4*)&Ws[k*FO + c0];
            acc0[0]=fmaf(x0,w4.x,acc0[0]); acc0[1]=fmaf(x0,w4.y,acc0[1]);
            acc0[2]=fmaf(x0,w4.z,acc0[2]); acc0[3]=fmaf(x0,w4.w,acc0[3]);
            acc1[0]=fmaf(x1,w4.x,acc1[0]); acc1[1]=fmaf(x1,w4.y,acc1[1]);
            acc1[2]=fmaf(x1,w4.z,acc1[2]); acc1[3]=fmaf(x1,w4.w,acc1[3]);
        }
        __syncthreads();
    }
    float* o0 = feats + ((size_t)(row0 + rg*2 + 0)*2 + h)*FO + c0;
    float* o1 = feats + ((size_t)(row0 + rg*2 + 1)*2 + h)*FO + c0;
    *(float4*)o0 = make_float4(acc0[0],acc0[1],acc0[2],acc0[3]);
    *(float4*)o1 = make_float4(acc1[0],acc1[1],acc1[2],acc1[3]);
}

// ---------------- Kernel 2: CSR build — batched loads + ballot compaction ----------------
__global__ __launch_bounds__(256) void csr_kernel(
    const float* __restrict__ A,     // [8192][8192] exact 0/1
    int* __restrict__ cnt,           // [8192]
    int* __restrict__ nbr)           // [8192][CAP]
{
    __shared__ int s_n[CAP];
    __shared__ int s_c;
    const int i = blockIdx.x, t = threadIdx.x;
    const int w = t >> 6, l = t & 63;
    if (t == 0) s_c = 0;
    __syncthreads();

    const float4* Arow = (const float4*)(A + (size_t)i*NN + w*2048);
    float4 v[8];
    #pragma unroll
    for (int it=0; it<8; ++it) v[it] = Arow[it*64 + l];   // 8 loads in flight, 1KB/wave each

    const unsigned long long ltmask = (1ull << l) - 1ull;
    #pragma unroll
    for (int it=0; it<8; ++it){
        int colb = w*2048 + it*256 + l*4;
        float vals[4] = {v[it].x, v[it].y, v[it].z, v[it].w};
        #pragma unroll
        for (int e=0; e<4; ++e){
            bool nz = (vals[e] != 0.0f);
            unsigned long long m = __ballot(nz);
            int base = 0;
            if (l == 0) base = atomicAdd(&s_c, __popcll(m));
            base = __shfl(base, 0, 64);
            if (nz){
                int p = base + __popcll(m & ltmask);
                if (p < CAP) s_n[p] = colb + e;
            }
        }
    }
    __syncthreads();
    int n = min(s_c, CAP);
    if (t == 0) cnt[i] = n;
    for (int k=t; k<n; k+=256) nbr[(size_t)i*CAP + k] = s_n[k];
}

// ---------------- Kernel 3: block-per-row attention, chunked online softmax ----------------
// f-tile read ONCE coalesced; scores computed during load (shuffle-reduced); no gathers.
__global__ __launch_bounds__(256) void attn_kernel(
    const float* __restrict__ feats, // [8192][2][64]
    const float* __restrict__ av,    // [2][64]
    const float* __restrict__ bv,    // [2][64]
    const int* __restrict__ cnt,
    const int* __restrict__ nbr,
    float* __restrict__ out)         // [8192][128]
{
    __shared__ float fls[64*132];    // f-tile: 64 nbrs x 128 (stride 132, 16B-aligned rows)
    __shared__ int   nbrl[CAP];
    __shared__ float ssh[2][64];     // raw scores per chunk
    __shared__ float psh[2][64];     // softmax numerators per chunk
    __shared__ float bc[4];          // alpha0, alpha1, l0, l1
    __shared__ float part[4*128];    // per-k-group partial aggregates

    const int i = blockIdx.x, t = threadIdx.x;
    const int lane32 = t & 31;
    const int nbloc  = t >> 5;       // 0..7: neighbor sub-slot
    const int gag    = t >> 6;       // 0..3: aggregate k-group
    const int op     = t & 63;       // aggregate output pair index

    // q slice in registers: this thread's 4 elems of q = feats[i]*a
    float4 qa = *(const float4*)&av[lane32*4];
    float4 qf = *(const float4*)&feats[(size_t)i*128 + lane32*4];
    float4 q4 = make_float4(qf.x*qa.x, qf.y*qa.y, qf.z*qa.z, qf.w*qa.w);

    const int n = cnt[i];
    for (int k=t; k<n; k+=256) nbrl[k] = nbr[(size_t)i*CAP + k];
    __syncthreads();

    float m0 = -1e30f, m1 = -1e30f, l0 = 0.f, l1 = 0.f;  // live in wave0
    float2 acc = make_float2(0.f, 0.f);
    const int nch = (n + 63) >> 6;

    for (int c=0; c<nch; ++c){
        const int base = c*64;
        const int nv = min(n - base, 64);

        // ---- load f-tile coalesced + compute scores in-flight ----
        #pragma unroll
        for (int it=0; it<8; ++it){
            int kk = it*8 + nbloc;
            int j = (kk < nv) ? nbrl[base + kk] : i;
            float4 f4 = *(const float4*)&feats[(size_t)j*128 + lane32*4];
            *(float4*)&fls[kk*132 + lane32*4] = f4;
            float d = f4.x*q4.x + f4.y*q4.y + f4.z*q4.z + f4.w*q4.w;
            d += __shfl_xor(d, 1, 64);
            d += __shfl_xor(d, 2, 64);
            d += __shfl_xor(d, 4, 64);
            d += __shfl_xor(d, 8, 64);       // 16-lane halves: head0 in lane 0, head1 in lane 16
            if (lane32 == 0)  ssh[0][kk] = (kk < nv) ? d : -1e30f;
            if (lane32 == 16) ssh[1][kk] = (kk < nv) ? d : -1e30f;
        }
        __syncthreads();

        // ---- wave0: leaky relu + online-softmax update ----
        if (t < 64){
            float s0 = ssh[0][t]; s0 = (s0 >= 0.f) ? s0 : 0.2f*s0;
            float s1 = ssh[1][t]; s1 = (s1 >= 0.f) ? s1 : 0.2f*s1;
            float cm0 = s0, cm1 = s1;
            #pragma unroll
            for (int off=32; off; off>>=1){
                cm0 = fmaxf(cm0, __shfl_xor(cm0, off, 64));
                cm1 = fmaxf(cm1, __shfl_xor(cm1, off, 64));
            }
            float nm0 = fmaxf(m0, cm0), nm1 = fmaxf(m1, cm1);
            float al0 = __expf(m0 - nm0), al1 = __expf(m1 - nm1);
            float p0 = __expf(s0 - nm0), p1 = __expf(s1 - nm1);
            psh[0][t] = p0; psh[1][t] = p1;
            float sp0 = p0, sp1 = p1;
            #pragma unroll
            for (int off=32; off; off>>=1){
                sp0 += __shfl_xor(sp0, off, 64);
                sp1 += __shfl_xor(sp1, off, 64);
            }
            l0 = l0*al0 + sp0; l1 = l1*al1 + sp1;
            m0 = nm0; m1 = nm1;
            if (t == 0){ bc[0] = al0; bc[1] = al1; }
        }
        __syncthreads();

        // ---- aggregate from LDS tile (conflict-free float2 reads) ----
        const float alph = bc[op >> 5];
        const float* pr = psh[op >> 5];
        acc.x *= alph; acc.y *= alph;
        for (int k=gag; k<nv; k+=4){
            float p = pr[k];
            float2 f2 = *(const float2*)&fls[k*132 + op*2];
            acc.x = fmaf(p, f2.x, acc.x);
            acc.y = fmaf(p, f2.y, acc.y);
        }
        __syncthreads();   // protect fls/ssh/psh for next chunk
    }

    if (t == 0){ bc[2] = l0; bc[3] = l1; }
    *(float2*)&part[gag*128 + op*2] = acc;
    __syncthreads();

    if (t < 128){
        int o = t, h = o >> 6;
        float s = part[o] + part[128+o] + part[256+o] + part[384+o];
        float val = s / bc[2+h] + bv[o];
        out[(size_t)i*128 + o] = fmaxf(val, 0.f);
    }
}

extern "C" void kernel_launch(void* const* d_in, const int* in_sizes, int n_in,
                              void* d_out, int out_size, void* d_ws, size_t ws_size,
                              hipStream_t stream) {
    const float* X = (const float*)d_in[0];   // [8192,256]
    const float* A = (const float*)d_in[1];   // [8192,8192]
    const float* W = (const float*)d_in[2];   // [2,256,64]
    const float* b = (const float*)d_in[3];   // [2,64]
    const float* a = (const float*)d_in[4];   // [2,64]
    float* out = (float*)d_out;               // [8192,128]

    char* ws = (char*)d_ws;
    float* feats = (float*)ws;                            // 4 MB
    int*   cnt   = (int*)(ws + (size_t)NN*2*FO*4);        // 32 KB
    int*   nbrs  = (int*)(ws + (size_t)NN*2*FO*4 + NN*4); // 6.3 MB

    feats_kernel<<<dim3(NN/32, 2), 256, 0, stream>>>(X, W, feats);
    csr_kernel  <<<dim3(NN),       256, 0, stream>>>(A, cnt, nbrs);
    attn_kernel <<<dim3(NN),       256, 0, stream>>>(feats, a, b, cnt, nbrs, out);
}

// Round 5
// 428.504 us; speedup vs baseline: 1.4433x; 1.0963x over previous
//
#include <hip/hip_runtime.h>

#define NN 8192
#define FIN 256
#define FO 64
#define CAP 192   // max neighbors per row (mean ~83, sd ~9 -> +12 sigma headroom)

// ---------------- Kernel 1: feats[n][h][o] = sum_f X[n][f] * W[h][f][o] ----------------
__global__ __launch_bounds__(256) void feats_kernel(
    const float* __restrict__ X,     // [8192][256]
    const float* __restrict__ W,     // [2][256][64]
    float* __restrict__ feats)       // [8192][2][64] (head-major halves per node)
{
    __shared__ float Ws[128*FO];     // [k][o], 32KB
    __shared__ float Xs[32*132];     // [r][k], stride 132
    const int h = blockIdx.y;
    const int row0 = blockIdx.x * 32;
    const int t = threadIdx.x;
    const int rg = t >> 4;
    const int c0 = (t & 15) << 2;
    float acc0[4] = {0.f,0.f,0.f,0.f};
    float acc1[4] = {0.f,0.f,0.f,0.f};

    for (int kp = 0; kp < 2; ++kp){
        const int kb = kp * 128;
        const float* Wh = W + h*FIN*FO + kb*FO;
        #pragma unroll
        for (int it=0; it<8; ++it){
            int flat = (it*256 + t)*4;
            *(float4*)&Ws[flat] = *(const float4*)&Wh[flat];
        }
        #pragma unroll
        for (int it=0; it<4; ++it){
            int flat = (it*256 + t)*4;
            int r = flat >> 7, f0 = flat & 127;
            *(float4*)&Xs[r*132 + f0] = *(const float4*)&X[(size_t)(row0+r)*FIN + kb + f0];
        }
        __syncthreads();
        const float* xp0 = &Xs[(rg*2+0)*132];
        const float* xp1 = &Xs[(rg*2+1)*132];
        #pragma unroll 4
        for (int k=0; k<128; ++k){
            float x0 = xp0[k], x1 = xp1[k];
            float4 w4 = *(const float4*)&Ws[k*FO + c0];
            acc0[0]=fmaf(x0,w4.x,acc0[0]); acc0[1]=fmaf(x0,w4.y,acc0[1]);
            acc0[2]=fmaf(x0,w4.z,acc0[2]); acc0[3]=fmaf(x0,w4.w,acc0[3]);
            acc1[0]=fmaf(x1,w4.x,acc1[0]); acc1[1]=fmaf(x1,w4.y,acc1[1]);
            acc1[2]=fmaf(x1,w4.z,acc1[2]); acc1[3]=fmaf(x1,w4.w,acc1[3]);
        }
        __syncthreads();
    }
    float* o0 = feats + ((size_t)(row0 + rg*2 + 0)*2 + h)*FO + c0;
    float* o1 = feats + ((size_t)(row0 + rg*2 + 1)*2 + h)*FO + c0;
    *(float4*)o0 = make_float4(acc0[0],acc0[1],acc0[2],acc0[3]);
    *(float4*)o1 = make_float4(acc1[0],acc1[1],acc1[2],acc1[3]);
}

// ---------------- Kernel 2: fused scan + attention, one block (512 thr) per row ----------------
__global__ __launch_bounds__(512) void gat_kernel(
    const float* __restrict__ A,     // [8192][8192] exact 0/1
    const float* __restrict__ feats, // [8192][2][64]
    const float* __restrict__ av,    // [2][64]
    const float* __restrict__ bv,    // [2][64]
    float* __restrict__ out)         // [8192][128]
{
    __shared__ int   nsh[CAP];
    __shared__ float s0[CAP], s1[CAP];
    __shared__ float part[4*128];
    __shared__ float red[2];
    __shared__ int   s_c;

    const int i = blockIdx.x, t = threadIdx.x;
    const int l  = t & 63;           // lane in wave
    const int wv = t >> 6;           // wave id 0..7
    const int gi = t >> 5, l32 = t & 31;   // 16 score groups of 32 lanes

    // q slice (both heads): lanes 0-15 of each group cover head0, 16-31 head1
    float4 qa = *(const float4*)&av[l32*4];
    float4 qf = *(const float4*)&feats[(size_t)i*128 + l32*4];
    const float4 q4 = make_float4(qf.x*qa.x, qf.y*qa.y, qf.z*qa.z, qf.w*qa.w);

    if (t == 0) s_c = 0;
    __syncthreads();

    // ---- Phase A: scan A-row (batched loads), ballot compaction ----
    const float4* Arow4 = (const float4*)(A + (size_t)i*NN);
    float4 v[4];
    #pragma unroll
    for (int r=0; r<4; ++r) v[r] = Arow4[r*512 + t];   // 8KB/wave in flight

    const unsigned long long ltmask = (1ull << l) - 1ull;
    #pragma unroll
    for (int r=0; r<4; ++r){
        float vals[4] = {v[r].x, v[r].y, v[r].z, v[r].w};
        #pragma unroll
        for (int e=0; e<4; ++e){
            bool nz = (vals[e] != 0.0f);
            unsigned long long m = __ballot(nz);
            int base = 0;
            if (l == 0) base = atomicAdd(&s_c, __popcll(m));
            base = __shfl(base, 0, 64);
            if (nz){
                int p = base + __popcll(m & ltmask);
                if (p < CAP) nsh[p] = (r*512 + t)*4 + e;
            }
        }
    }
    __syncthreads();
    const int n = min(s_c, CAP);

    // ---- Phase B: scores, one neighbor per 32-lane group (coalesced L2 reads) ----
    for (int k=gi; k<n; k+=16){
        int j = nsh[k];
        float4 f4 = *(const float4*)&feats[(size_t)j*128 + l32*4];
        float d = f4.x*q4.x + f4.y*q4.y + f4.z*q4.z + f4.w*q4.w;
        d += __shfl_xor(d, 1, 64);
        d += __shfl_xor(d, 2, 64);
        d += __shfl_xor(d, 4, 64);
        d += __shfl_xor(d, 8, 64);       // full sum within each 16-lane half
        d = (d >= 0.f) ? d : 0.2f*d;
        if (l32 == 0)  s0[k] = d;
        if (l32 == 16) s1[k] = d;
    }
    __syncthreads();

    // ---- softmax (wave0 -> head0, wave1 -> head1), in-place p = exp(s-m) ----
    if (wv < 2){
        float* ss = wv ? s1 : s0;
        float m = -1e30f;
        for (int k=l; k<n; k+=64) m = fmaxf(m, ss[k]);
        #pragma unroll
        for (int off=32; off; off>>=1) m = fmaxf(m, __shfl_xor(m, off, 64));
        float sum = 0.f;
        for (int k=l; k<n; k+=64){ float p = __expf(ss[k]-m); ss[k] = p; sum += p; }
        #pragma unroll
        for (int off=32; off; off>>=1) sum += __shfl_xor(sum, off, 64);
        if (l == 0) red[wv] = sum;
    }
    __syncthreads();

    // ---- Phase C: aggregate, 4-way k-split, coalesced feats rows ----
    const int op = t & 127, g = t >> 7;
    const float* ps = (op >= 64) ? s1 : s0;
    float acc = 0.f;
    for (int k=g; k<n; k+=4){
        int j = nsh[k];
        acc = fmaf(ps[k], feats[(size_t)j*128 + op], acc);
    }
    part[g*128 + op] = acc;
    __syncthreads();

    if (t < 128){
        float num = part[t] + part[128+t] + part[256+t] + part[384+t];
        float val = num / red[t>>6] + bv[t];
        out[(size_t)i*128 + t] = fmaxf(val, 0.f);
    }
}

extern "C" void kernel_launch(void* const* d_in, const int* in_sizes, int n_in,
                              void* d_out, int out_size, void* d_ws, size_t ws_size,
                              hipStream_t stream) {
    const float* X = (const float*)d_in[0];   // [8192,256]
    const float* A = (const float*)d_in[1];   // [8192,8192]
    const float* W = (const float*)d_in[2];   // [2,256,64]
    const float* b = (const float*)d_in[3];   // [2,64]
    const float* a = (const float*)d_in[4];   // [2,64]
    float* out = (float*)d_out;               // [8192,128]

    float* feats = (float*)d_ws;              // 4 MB

    feats_kernel<<<dim3(NN/32, 2), 256, 0, stream>>>(X, W, feats);
    gat_kernel  <<<dim3(NN),       512, 0, stream>>>(A, feats, a, b, out);
}

// Round 7
// 391.865 us; speedup vs baseline: 1.5783x; 1.0935x over previous
//
#include <hip/hip_runtime.h>

#define NN 8192
#define FIN 256
#define FO 64
#define CAP 192   // max neighbors per row (mean ~83, sd ~9 -> +12 sigma headroom)

typedef float nf4 __attribute__((ext_vector_type(4)));  // native vec for nontemporal builtin

// ---------------- Kernel 1: feats[n][h][o] = sum_f X[n][f] * W[h][f][o] ----------------
__global__ __launch_bounds__(256) void feats_kernel(
    const float* __restrict__ X,     // [8192][256]
    const float* __restrict__ W,     // [2][256][64]
    float* __restrict__ feats)       // [8192][2][64] (head-major halves per node)
{
    __shared__ float Ws[128*FO];     // [k][o], 32KB
    __shared__ float Xs[32*132];     // [r][k], stride 132
    const int h = blockIdx.y;
    const int row0 = blockIdx.x * 32;
    const int t = threadIdx.x;
    const int rg = t >> 4;
    const int c0 = (t & 15) << 2;
    float acc0[4] = {0.f,0.f,0.f,0.f};
    float acc1[4] = {0.f,0.f,0.f,0.f};

    for (int kp = 0; kp < 2; ++kp){
        const int kb = kp * 128;
        const float* Wh = W + h*FIN*FO + kb*FO;
        #pragma unroll
        for (int it=0; it<8; ++it){
            int flat = (it*256 + t)*4;
            *(float4*)&Ws[flat] = *(const float4*)&Wh[flat];
        }
        #pragma unroll
        for (int it=0; it<4; ++it){
            int flat = (it*256 + t)*4;
            int r = flat >> 7, f0 = flat & 127;
            *(float4*)&Xs[r*132 + f0] = *(const float4*)&X[(size_t)(row0+r)*FIN + kb + f0];
        }
        __syncthreads();
        const float* xp0 = &Xs[(rg*2+0)*132];
        const float* xp1 = &Xs[(rg*2+1)*132];
        #pragma unroll 4
        for (int k=0; k<128; ++k){
            float x0 = xp0[k], x1 = xp1[k];
            float4 w4 = *(const float4*)&Ws[k*FO + c0];
            acc0[0]=fmaf(x0,w4.x,acc0[0]); acc0[1]=fmaf(x0,w4.y,acc0[1]);
            acc0[2]=fmaf(x0,w4.z,acc0[2]); acc0[3]=fmaf(x0,w4.w,acc0[3]);
            acc1[0]=fmaf(x1,w4.x,acc1[0]); acc1[1]=fmaf(x1,w4.y,acc1[1]);
            acc1[2]=fmaf(x1,w4.z,acc1[2]); acc1[3]=fmaf(x1,w4.w,acc1[3]);
        }
        __syncthreads();
    }
    float* o0 = feats + ((size_t)(row0 + rg*2 + 0)*2 + h)*FO + c0;
    float* o1 = feats + ((size_t)(row0 + rg*2 + 1)*2 + h)*FO + c0;
    *(float4*)o0 = make_float4(acc0[0],acc0[1],acc0[2],acc0[3]);
    *(float4*)o1 = make_float4(acc1[0],acc1[1],acc1[2],acc1[3]);
}

// ---------------- Kernel 2: fused scan + attention, one block (512 thr) per row ----------------
__global__ __launch_bounds__(512) void gat_kernel(
    const float* __restrict__ A,     // [8192][8192] exact 0/1
    const float* __restrict__ feats, // [8192][2][64]
    const float* __restrict__ av,    // [2][64]
    const float* __restrict__ bv,    // [2][64]
    float* __restrict__ out)         // [8192][128]
{
    __shared__ int   nsh[CAP];
    __shared__ float s0[CAP], s1[CAP];
    __shared__ float part[8*128];
    __shared__ float red[2];
    __shared__ int   s_c;

    const int i = blockIdx.x, t = threadIdx.x;
    const int l  = t & 63;                 // lane in wave
    const int wv = t >> 6;                 // wave id 0..7
    const int gi = t >> 5, l32 = t & 31;   // 16 score groups of 32 lanes

    // q slice (both heads): 16-lane halves of each 32-lane group
    float4 qa = *(const float4*)&av[l32*4];
    float4 qf = *(const float4*)&feats[(size_t)i*128 + l32*4];
    const float4 q4 = make_float4(qf.x*qa.x, qf.y*qa.y, qf.z*qa.z, qf.w*qa.w);

    if (t == 0) s_c = 0;
    __syncthreads();

    // ---- Phase A: batched nontemporal scan + ballot compaction (1 atomic/wave/round) ----
    const nf4* Arow4 = (const nf4*)(A + (size_t)i*NN);
    nf4 v[4];
    #pragma unroll
    for (int r=0; r<4; ++r) v[r] = __builtin_nontemporal_load(&Arow4[r*512 + t]);

    const unsigned long long ltmask = (1ull << l) - 1ull;
    #pragma unroll
    for (int r=0; r<4; ++r){
        unsigned long long m0 = __ballot(v[r].x != 0.0f);
        unsigned long long m1 = __ballot(v[r].y != 0.0f);
        unsigned long long m2 = __ballot(v[r].z != 0.0f);
        unsigned long long m3 = __ballot(v[r].w != 0.0f);
        int p0 = __popcll(m0), p1 = __popcll(m1), p2 = __popcll(m2), p3 = __popcll(m3);
        int base = 0;
        if (l == 0) base = atomicAdd(&s_c, p0+p1+p2+p3);
        base = __shfl(base, 0, 64);
        const int colb = (r*512 + t)*4;
        if ((m0>>l)&1){ int p = base + __popcll(m0 & ltmask); if (p<CAP) nsh[p] = colb;   } base += p0;
        if ((m1>>l)&1){ int p = base + __popcll(m1 & ltmask); if (p<CAP) nsh[p] = colb+1; } base += p1;
        if ((m2>>l)&1){ int p = base + __popcll(m2 & ltmask); if (p<CAP) nsh[p] = colb+2; } base += p2;
        if ((m3>>l)&1){ int p = base + __popcll(m3 & ltmask); if (p<CAP) nsh[p] = colb+3; }
    }
    __syncthreads();
    const int n = min(s_c, CAP);

    // ---- Phase B: scores; each 32-lane group takes contiguous chunks of 4 (batched gathers) ----
    for (int k0 = gi*4; k0 < n; k0 += 64){
        const int kn = min(4, n - k0);
        float4 f[4];
        #pragma unroll
        for (int u=0; u<4; ++u){
            int j = (u < kn) ? nsh[k0+u] : i;
            f[u] = *(const float4*)&feats[(size_t)j*128 + l32*4];
        }
        #pragma unroll
        for (int u=0; u<4; ++u){
            float d = f[u].x*q4.x + f[u].y*q4.y + f[u].z*q4.z + f[u].w*q4.w;
            d += __shfl_xor(d, 1, 64);
            d += __shfl_xor(d, 2, 64);
            d += __shfl_xor(d, 4, 64);
            d += __shfl_xor(d, 8, 64);       // full sum within each 16-lane half
            d = (d >= 0.f) ? d : 0.2f*d;
            if (u < kn){
                if (l32 == 0)  s0[k0+u] = d;
                if (l32 == 16) s1[k0+u] = d;
            }
        }
    }
    __syncthreads();

    // ---- softmax (wave0 -> head0, wave1 -> head1), in-place p = exp(s-m) ----
    if (wv < 2){
        float* ss = wv ? s1 : s0;
        float m = -1e30f;
        for (int k=l; k<n; k+=64) m = fmaxf(m, ss[k]);
        #pragma unroll
        for (int off=32; off; off>>=1) m = fmaxf(m, __shfl_xor(m, off, 64));
        float sum = 0.f;
        for (int k=l; k<n; k+=64){ float p = __expf(ss[k]-m); ss[k] = p; sum += p; }
        #pragma unroll
        for (int off=32; off; off>>=1) sum += __shfl_xor(sum, off, 64);
        if (l == 0) red[wv] = sum;
    }
    __syncthreads();

    // ---- Phase C: aggregate, 8-way k-split, float2/thread, 4-way batched gathers ----
    const int g8 = t >> 6;           // k-group 0..7
    const int o2 = (t & 63) * 2;     // output pair
    const float* ps = (o2 >= 64) ? s1 : s0;
    float2 acc = make_float2(0.f, 0.f);
    int k = g8;
    for (; k + 24 < n; k += 32){
        int j0 = nsh[k], j1 = nsh[k+8], j2 = nsh[k+16], j3 = nsh[k+24];
        float2 f0 = *(const float2*)&feats[(size_t)j0*128 + o2];
        float2 f1 = *(const float2*)&feats[(size_t)j1*128 + o2];
        float2 f2 = *(const float2*)&feats[(size_t)j2*128 + o2];
        float2 f3 = *(const float2*)&feats[(size_t)j3*128 + o2];
        float p0 = ps[k], p1 = ps[k+8], p2 = ps[k+16], p3 = ps[k+24];
        acc.x = fmaf(p0, f0.x, acc.x); acc.y = fmaf(p0, f0.y, acc.y);
        acc.x = fmaf(p1, f1.x, acc.x); acc.y = fmaf(p1, f1.y, acc.y);
        acc.x = fmaf(p2, f2.x, acc.x); acc.y = fmaf(p2, f2.y, acc.y);
        acc.x = fmaf(p3, f3.x, acc.x); acc.y = fmaf(p3, f3.y, acc.y);
    }
    for (; k < n; k += 8){
        int j = nsh[k];
        float2 f = *(const float2*)&feats[(size_t)j*128 + o2];
        float p = ps[k];
        acc.x = fmaf(p, f.x, acc.x); acc.y = fmaf(p, f.y, acc.y);
    }
    *(float2*)&part[g8*128 + o2] = acc;
    __syncthreads();

    if (t < 128){
        float num = part[t]       + part[128+t] + part[256+t] + part[384+t]
                  + part[512+t]   + part[640+t] + part[768+t] + part[896+t];
        float val = num / red[t>>6] + bv[t];
        out[(size_t)i*128 + t] = fmaxf(val, 0.f);
    }
}

extern "C" void kernel_launch(void* const* d_in, const int* in_sizes, int n_in,
                              void* d_out, int out_size, void* d_ws, size_t ws_size,
                              hipStream_t stream) {
    const float* X = (const float*)d_in[0];   // [8192,256]
    const float* A = (const float*)d_in[1];   // [8192,8192]
    const float* W = (const float*)d_in[2];   // [2,256,64]
    const float* b = (const float*)d_in[3];   // [2,64]
    const float* a = (const float*)d_in[4];   // [2,64]
    float* out = (float*)d_out;               // [8192,128]

    float* feats = (float*)d_ws;              // 4 MB

    feats_kernel<<<dim3(NN/32, 2), 256, 0, stream>>>(X, W, feats);
    gat_kernel  <<<dim3(NN),       512, 0, stream>>>(A, feats, a, b, out);
}